// Round 9
// baseline (545.550 us; speedup 1.0000x reference)
//
#include <hip/hip_runtime.h>

// z: [16,4096,256] fp32 -> N=65536 rows, d=256
// embedding: [256,1024], cluster_size: [1024], embedding_mean: [256,1024]

#define DECAYC 0.99f
#define EPSQ 1e-5f

typedef unsigned short ushort_t;
typedef __attribute__((ext_vector_type(8))) short bf16x8;
typedef __attribute__((ext_vector_type(4))) float f32x4;
typedef unsigned long long u64;

__device__ __forceinline__ ushort_t f2bf(float x) {
    unsigned u = __float_as_uint(x);
    unsigned r = (u + 0x7FFFu + ((u >> 16) & 1u)) >> 16;   // RNE
    return (ushort_t)r;
}
__device__ __forceinline__ float bf2f(ushort_t h) {
    return __uint_as_float(((unsigned)h) << 16);
}
__device__ __forceinline__ u64 umin64(u64 a, u64 b) { return a < b ? a : b; }

// ---------------- E-side prep (fused): ET + colnorm + Eph/Epl + zero stats ----------------
__global__ __launch_bounds__(256) void prep_E_kernel(const float* __restrict__ E,
                                                     float* __restrict__ ET,
                                                     float* __restrict__ colnorm,
                                                     ushort_t* __restrict__ Eph,
                                                     ushort_t* __restrict__ Epl,
                                                     int* __restrict__ counts,
                                                     float* __restrict__ lossSum) {
    int n = blockIdx.x;
    int d = threadIdx.x;
    if (d == 0) counts[n] = 0;
    if (n == 0 && d == 1) lossSum[0] = 0.f;
    float v = E[d * 1024 + n];
    ET[n * 256 + d] = v;
    ushort_t h = f2bf(v);
    ushort_t l = f2bf(v - bf2f(h));
    size_t pi = ((size_t)(d >> 3) * 1024 + n) * 8 + (d & 7);
    Eph[pi] = h;
    Epl[pi] = l;
    __shared__ float red[256];
    red[d] = v * v;
    __syncthreads();
    for (int o = 128; o > 0; o >>= 1) {
        if (d < o) red[d] += red[d + o];
        __syncthreads();
    }
    if (d == 0) colnorm[n] = red[0];
}

// ---------------- MFMA distance + argmin + fused gather/loss/hist ----------------
// Block: 64 rows x 1024 codes, 512 threads = 8 waves in 2(row)x4(code) grid.
// Wave tile: 32 rows x 32 codes -> acc[2][2] (16 VGPR) + best[2][2] (8 VGPR):
// low register pressure (round-8 spill post-mortem). LDS ~68 KB -> 2 blocks/CU
// -> 16 waves/CU TLP to cover the barrier-free global B loads.
// Loss computed from the winning key: min||z-e||^2 = ||z||^2 + (cn - 2*dot).
__global__ __launch_bounds__(512, 4) void dist_mfma_kernel(const float* __restrict__ z,
                                                           const ushort_t* __restrict__ Eph,
                                                           const ushort_t* __restrict__ Epl,
                                                           const float* __restrict__ colnorm,
                                                           const float* __restrict__ ET,
                                                           float* __restrict__ out0,
                                                           float* __restrict__ lossSum,
                                                           int* __restrict__ counts,
                                                           int* __restrict__ idxOut) {
    __shared__ __align__(16) ushort_t Ah[16384];   // slots (kq*64+r)*8, 32 KB
    __shared__ __align__(16) ushort_t Al[16384];
    __shared__ u64 bl[4][64];                      // per-wcol row minima
    __shared__ float zpart[8][64];                 // per-wave ||z||^2 partials
    __shared__ int kArr[64];
    __shared__ float sred[8];

    const int t = threadIdx.x;
    const int lane = t & 63;
    const int w = t >> 6;          // wave 0..7
    const int wrow = w >> 2;       // 0..1  (rows wrow*32..)
    const int wcol = w & 3;        // 0..3  (codes wcol*32.. within chunk)
    const int n16 = lane & 15;
    const int q = lane >> 4;       // 0..3
    const int rowBase = blockIdx.x * 64;

    // ---- one-time: convert 64 z rows to bf16 hi/lo in LDS + ||z||^2 partials ----
    float zsq = 0.f;
#pragma unroll
    for (int i = 0; i < 4; ++i) {
        int s = i * 512 + t;       // slot: kq = s>>6 (0..31), r = s&63
        int kq = s >> 6;
        int r = s & 63;
        const float* gp = z + (size_t)(rowBase + r) * 256 + kq * 8;
        float4 v0 = *(const float4*)gp;
        float4 v1 = *(const float4*)(gp + 4);
        float vv[8] = {v0.x, v0.y, v0.z, v0.w, v1.x, v1.y, v1.z, v1.w};
        ushort_t hh[8], ll[8];
#pragma unroll
        for (int j = 0; j < 8; ++j) {
            hh[j] = f2bf(vv[j]);
            ll[j] = f2bf(vv[j] - bf2f(hh[j]));
            zsq += vv[j] * vv[j];
        }
        ushort4 h0 = {hh[0], hh[1], hh[2], hh[3]}, h1 = {hh[4], hh[5], hh[6], hh[7]};
        ushort4 l0 = {ll[0], ll[1], ll[2], ll[3]}, l1 = {ll[4], ll[5], ll[6], ll[7]};
        *(ushort4*)&Ah[s * 8] = h0;
        *(ushort4*)&Ah[s * 8 + 4] = h1;
        *(ushort4*)&Al[s * 8] = l0;
        *(ushort4*)&Al[s * 8 + 4] = l1;
    }
    zpart[w][lane] = zsq;          // r = lane for every i (i*512 ≡ 0 mod 64)
    __syncthreads();

    u64 best[2][4];
#pragma unroll
    for (int rt = 0; rt < 2; ++rt)
#pragma unroll
        for (int reg = 0; reg < 4; ++reg) best[rt][reg] = ~0ull;

    for (int cb = 0; cb < 8; ++cb) {
        const int cBase = cb * 128 + wcol * 32;    // this wave's 32-code stripe
        f32x4 acc[2][2];
#pragma unroll
        for (int rt = 0; rt < 2; ++rt)
#pragma unroll
            for (int ct = 0; ct < 2; ++ct) acc[rt][ct] = (f32x4){0.f, 0.f, 0.f, 0.f};

#pragma unroll
        for (int ks = 0; ks < 8; ++ks) {
            bf16x8 bfh[2], bfl[2];
            const size_t bbase = ((size_t)(ks * 4 + q) * 1024 + cBase + n16) * 8;
#pragma unroll
            for (int ct = 0; ct < 2; ++ct) {
                bfh[ct] = *(const bf16x8*)(Eph + bbase + ct * 128);
                bfl[ct] = *(const bf16x8*)(Epl + bbase + ct * 128);
            }
            bf16x8 afh[2], afl[2];
#pragma unroll
            for (int rt = 0; rt < 2; ++rt) {
                int ao = ((ks * 4 + q) * 64 + wrow * 32 + rt * 16 + n16) * 8;
                afh[rt] = *(const bf16x8*)&Ah[ao];
                afl[rt] = *(const bf16x8*)&Al[ao];
            }
#pragma unroll
            for (int rt = 0; rt < 2; ++rt)
#pragma unroll
                for (int ct = 0; ct < 2; ++ct) {
                    acc[rt][ct] = __builtin_amdgcn_mfma_f32_16x16x32_bf16(afh[rt], bfh[ct], acc[rt][ct], 0, 0, 0);
                    acc[rt][ct] = __builtin_amdgcn_mfma_f32_16x16x32_bf16(afh[rt], bfl[ct], acc[rt][ct], 0, 0, 0);
                    acc[rt][ct] = __builtin_amdgcn_mfma_f32_16x16x32_bf16(afl[rt], bfh[ct], acc[rt][ct], 0, 0, 0);
                }
        }

        // lane-local argmin update (no cross-lane work inside the cb loop)
        float cn[2];
#pragma unroll
        for (int ct = 0; ct < 2; ++ct) cn[ct] = colnorm[cBase + ct * 16 + n16];
#pragma unroll
        for (int rt = 0; rt < 2; ++rt)
#pragma unroll
            for (int reg = 0; reg < 4; ++reg) {
                u64 b = best[rt][reg];
#pragma unroll
                for (int ct = 0; ct < 2; ++ct) {
                    float dist = cn[ct] - 2.f * acc[rt][ct][reg];
                    unsigned fb = __float_as_uint(dist);
                    unsigned sk = (fb & 0x80000000u) ? ~fb : (fb | 0x80000000u);
                    unsigned code = (unsigned)(cBase + ct * 16 + n16);
                    b = umin64(b, ((u64)sk << 32) | code);
                }
                best[rt][reg] = b;
            }
    }

    // one-time cross-lane reduction within each 16-lane col group
#pragma unroll
    for (int rt = 0; rt < 2; ++rt)
#pragma unroll
        for (int reg = 0; reg < 4; ++reg) {
            u64 b = best[rt][reg];
            b = umin64(b, __shfl_xor(b, 1, 64));
            b = umin64(b, __shfl_xor(b, 2, 64));
            b = umin64(b, __shfl_xor(b, 4, 64));
            b = umin64(b, __shfl_xor(b, 8, 64));
            best[rt][reg] = b;
        }
    if (n16 == 0) {
#pragma unroll
        for (int rt = 0; rt < 2; ++rt)
#pragma unroll
            for (int reg = 0; reg < 4; ++reg)
                bl[wcol][wrow * 32 + rt * 16 + q * 4 + reg] = best[rt][reg];
    }
    __syncthreads();

    // ---- epilogue: merge wcol stripes, decode key -> code + loss, hist ----
    if (t < 64) {
        u64 b = umin64(umin64(bl[0][t], bl[1][t]), umin64(bl[2][t], bl[3][t]));
        int k = (int)(unsigned)(b & 0xFFFFFFFFull);
        unsigned sk = (unsigned)(b >> 32);
        unsigned fb = (sk & 0x80000000u) ? (sk ^ 0x80000000u) : ~sk;
        float zn = zpart[0][t] + zpart[1][t] + zpart[2][t] + zpart[3][t]
                 + zpart[4][t] + zpart[5][t] + zpart[6][t] + zpart[7][t];
        float dmin = __uint_as_float(fb) + zn;
        idxOut[rowBase + t] = k;
        kArr[t] = k;
        atomicAdd(counts + k, 1);
        float v = dmin;
#pragma unroll
        for (int o = 32; o > 0; o >>= 1) v += __shfl_down(v, o, 64);
        if (t == 0) sred[0] = v;
    }
    __syncthreads();
    if (t == 0) atomicAdd(lossSum, sred[0]);

    // ---- gather z_q: wave w writes rows w*8..w*8+7 ----
#pragma unroll
    for (int i = 0; i < 8; ++i) {
        int r = w * 8 + i;
        int k = kArr[r];
        float4 qv = *(const float4*)(ET + (size_t)k * 256 + lane * 4);
        *(float4*)(out0 + (size_t)(rowBase + r) * 256 + lane * 4) = qv;
    }
}

// ---------------- prefix scan + cluster_size_new + n + loss finalize ----------------
__global__ __launch_bounds__(1024) void prefix_csn_kernel(const int* __restrict__ counts,
                                                          const float* __restrict__ cluster_size,
                                                          const float* __restrict__ lossSum,
                                                          int* __restrict__ offsets,
                                                          int* __restrict__ cursor,
                                                          float* __restrict__ out3,
                                                          float* __restrict__ out1,
                                                          float* __restrict__ nOut) {
    __shared__ int sbuf[1024];
    int t = threadIdx.x;
    int c = counts[t];
    sbuf[t] = c;
    __syncthreads();
    for (int off = 1; off < 1024; off <<= 1) {
        int v = (t >= off) ? sbuf[t - off] : 0;
        __syncthreads();
        sbuf[t] += v;
        __syncthreads();
    }
    offsets[t] = sbuf[t] - c;
    if (t == 1023) offsets[1024] = sbuf[1023];
    cursor[t] = 0;

    float cn = cluster_size[t] * DECAYC + (1.f - DECAYC) * (float)c;
    out3[t] = cn;
    float v = cn;
#pragma unroll
    for (int o = 32; o > 0; o >>= 1) v += __shfl_down(v, o, 64);
    __shared__ float fbuf[16];
    int lane = t & 63, wv = t >> 6;
    if (lane == 0) fbuf[wv] = v;
    __syncthreads();
    if (t == 0) {
        float n = 0.f;
#pragma unroll
        for (int i = 0; i < 16; ++i) n += fbuf[i];
        nOut[0] = n;
        out1[0] = 0.25f * lossSum[0] / 16777216.0f;
    }
}

// ---------------- scatter row ids into code-sorted order ----------------
__global__ __launch_bounds__(256) void scatter_sort_kernel(const int* __restrict__ idx,
                                                           const int* __restrict__ offsets,
                                                           int* __restrict__ cursor,
                                                           int* __restrict__ sorted) {
    int i = blockIdx.x * 256 + threadIdx.x;
    int k = idx[i];
    int pos = atomicAdd(cursor + k, 1);
    sorted[offsets[k] + pos] = i;
}

// ---------------- segmented sum: psum[(k*8+s)*256+d] (no atomics) ----------------
__global__ __launch_bounds__(256) void segsum_kernel(const float* __restrict__ z,
                                                     const int* __restrict__ sorted,
                                                     const int* __restrict__ offsets,
                                                     float* __restrict__ psum) {
    const int k = blockIdx.x >> 3;
    const int s = blockIdx.x & 7;
    const int t = threadIdx.x;
    const int lane = t & 63;
    const int w = t >> 6;
    const int start = offsets[k], end = offsets[k + 1];
    float4 acc = {0.f, 0.f, 0.f, 0.f};
    for (int j = start + s * 4 + w; j < end; j += 32) {
        int row = sorted[j];
        float4 v = *(const float4*)(z + (size_t)row * 256 + lane * 4);
        acc.x += v.x; acc.y += v.y; acc.z += v.z; acc.w += v.w;
    }
    __shared__ float red[4][256];
    *(float4*)&red[w][lane * 4] = acc;
    __syncthreads();
    float v = red[0][t] + red[1][t] + red[2][t] + red[3][t];
    psum[((size_t)k * 8 + s) * 256 + t] = v;
}

// ---------------- embedding_mean_new + embedding_new ----------------
__global__ __launch_bounds__(256) void final8_kernel(const float* __restrict__ embedding_mean,
                                                     const float* __restrict__ psum,
                                                     const float* __restrict__ csn,
                                                     const float* __restrict__ nPtr,
                                                     float* __restrict__ out2,
                                                     float* __restrict__ out4) {
    int tid = blockIdx.x * 256 + threadIdx.x;
    int d = tid >> 10;
    int k = tid & 1023;
    const float* p = psum + (size_t)k * 8 * 256 + d;
    float es = 0.f;
#pragma unroll
    for (int s = 0; s < 8; ++s) es += p[s * 256];
    float emn = embedding_mean[tid] * DECAYC + (1.f - DECAYC) * es;
    out4[tid] = emn;
    float n = nPtr[0];
    float c = csn[k];
    float cs = (c + EPSQ) / (n + 1024.f * EPSQ) * n;
    out2[tid] = emn / cs;
}

extern "C" void kernel_launch(void* const* d_in, const int* in_sizes, int n_in,
                              void* d_out, int out_size, void* d_ws, size_t ws_size,
                              hipStream_t stream) {
    const float* z = (const float*)d_in[0];
    const float* E = (const float*)d_in[1];
    const float* cluster_size = (const float*)d_in[2];
    const float* embedding_mean = (const float*)d_in[3];

    float* out0 = (float*)d_out;        // z_q_st
    float* out1 = out0 + 16777216;      // vq_loss
    float* out2 = out1 + 1;             // embedding_new
    float* out3 = out2 + 262144;        // cluster_size_new
    float* out4 = out3 + 1024;          // embedding_mean_new

    // ws layout (float units)
    float* ws = (float*)d_ws;
    float* colnorm = ws;                         // 1024
    int* idx = (int*)(ws + 1024);                // 65536
    int* counts = (int*)(ws + 66560);            // 1024  (zeroed in prep_E)
    float* lossSum = ws + 67584;                 // 1     (zeroed in prep_E)
    float* nOut = ws + 67585;                    // 1
    float* ET = ws + 67588;                      // 262144 fp32 [k][d]
    ushort_t* Eph = (ushort_t*)(ws + 329732);    // 262144 ushort
    ushort_t* Epl = (ushort_t*)(ws + 460804);    // 262144 ushort
    float* psum = ws + 591876;                   // 2097152
    int* sorted = (int*)(ws + 2689028);          // 65536
    int* offsets = (int*)(ws + 2754564);         // 1025
    int* cursor = (int*)(ws + 2755592);          // 1024

    prep_E_kernel<<<1024, 256, 0, stream>>>(E, ET, colnorm, Eph, Epl, counts, lossSum);
    dist_mfma_kernel<<<1024, 512, 0, stream>>>(z, Eph, Epl, colnorm, ET,
                                               out0, lossSum, counts, idx);
    prefix_csn_kernel<<<1, 1024, 0, stream>>>(counts, cluster_size, lossSum,
                                              offsets, cursor, out3, out1, nOut);
    scatter_sort_kernel<<<256, 256, 0, stream>>>(idx, offsets, cursor, sorted);
    segsum_kernel<<<8192, 256, 0, stream>>>(z, sorted, offsets, psum);
    final8_kernel<<<1024, 256, 0, stream>>>(embedding_mean, psum, out3, nOut, out2, out4);
}

// Round 10
// 322.496 us; speedup vs baseline: 1.6916x; 1.6916x over previous
//
#include <hip/hip_runtime.h>

// z: [16,4096,256] fp32 -> N=65536 rows, d=256
// embedding: [256,1024], cluster_size: [1024], embedding_mean: [256,1024]

#define DECAYC 0.99f
#define EPSQ 1e-5f

typedef unsigned short ushort_t;
typedef __attribute__((ext_vector_type(8))) short bf16x8;
typedef __attribute__((ext_vector_type(4))) float f32x4;
typedef unsigned long long u64;

__device__ __forceinline__ ushort_t f2bf(float x) {
    unsigned u = __float_as_uint(x);
    unsigned r = (u + 0x7FFFu + ((u >> 16) & 1u)) >> 16;   // RNE
    return (ushort_t)r;
}
__device__ __forceinline__ float bf2f(ushort_t h) {
    return __uint_as_float(((unsigned)h) << 16);
}
__device__ __forceinline__ u64 umin64(u64 a, u64 b) { return a < b ? a : b; }

// ---------------- E-side prep (fused): ET + colnorm + Eph/Epl + zero stats ----------------
__global__ __launch_bounds__(256) void prep_E_kernel(const float* __restrict__ E,
                                                     float* __restrict__ ET,
                                                     float* __restrict__ colnorm,
                                                     ushort_t* __restrict__ Eph,
                                                     ushort_t* __restrict__ Epl,
                                                     int* __restrict__ counts,
                                                     float* __restrict__ lossSum) {
    int n = blockIdx.x;
    int d = threadIdx.x;
    if (d == 0) counts[n] = 0;
    if (n == 0 && d == 1) lossSum[0] = 0.f;
    float v = E[d * 1024 + n];
    ET[n * 256 + d] = v;
    ushort_t h = f2bf(v);
    ushort_t l = f2bf(v - bf2f(h));
    size_t pi = ((size_t)(d >> 3) * 1024 + n) * 8 + (d & 7);
    Eph[pi] = h;
    Epl[pi] = l;
    __shared__ float red[256];
    red[d] = v * v;
    __syncthreads();
    for (int o = 128; o > 0; o >>= 1) {
        if (d < o) red[d] += red[d + o];
        __syncthreads();
    }
    if (d == 0) colnorm[n] = red[0];
}

// ---------------- MFMA distance + argmin + fused gather/loss/hist ----------------
// Block: 64 rows x 1024 codes. 256 thr = 4 waves, 2x2 of (32 rows x 64 codes)
// — round-6's proven tiling (dist=127us, VGPR=128, no catastrophic spill).
// A (z bf16 hi/lo) LDS-resident; B fragments direct global->VGPR, no barriers
// in the cb/ks loops. Epilogue (round-7 fusion): loss from the winning key
// (min||z-e||^2 = ||z||^2 + (cn - 2*dot)), histogram, z_q gather.
__global__ __launch_bounds__(256, 2) void dist_mfma_kernel(const float* __restrict__ z,
                                                           const ushort_t* __restrict__ Eph,
                                                           const ushort_t* __restrict__ Epl,
                                                           const float* __restrict__ colnorm,
                                                           const float* __restrict__ ET,
                                                           float* __restrict__ out0,
                                                           float* __restrict__ lossSum,
                                                           int* __restrict__ counts,
                                                           int* __restrict__ idxOut) {
    __shared__ __align__(16) ushort_t Ah[16384];   // slots (kq*64+r)*8, 32 KB
    __shared__ __align__(16) ushort_t Al[16384];
    __shared__ u64 bl[2][64];                      // per-wcol row minima
    __shared__ float zpart[4][64];                 // per-wave ||z||^2 partials
    __shared__ int kArr[64];
    __shared__ float sred[1];

    const int t = threadIdx.x;
    const int lane = t & 63;
    const int w = t >> 6;          // wave 0..3
    const int wrow = w >> 1;       // 0..1 (rows wrow*32..)
    const int wcol = w & 1;        // 0..1 (codes wcol*64.. within chunk)
    const int n16 = lane & 15;
    const int q = lane >> 4;       // 0..3
    const int rowBase = blockIdx.x * 64;

    // ---- one-time: convert 64 z rows to bf16 hi/lo in LDS + ||z||^2 partials ----
    float zsq = 0.f;
#pragma unroll
    for (int i = 0; i < 8; ++i) {
        int s = i * 256 + t;       // slot: kq = s>>6, r = s&63
        int kq = s >> 6;
        int r = s & 63;
        const float* gp = z + (size_t)(rowBase + r) * 256 + kq * 8;
        float4 v0 = *(const float4*)gp;
        float4 v1 = *(const float4*)(gp + 4);
        float vv[8] = {v0.x, v0.y, v0.z, v0.w, v1.x, v1.y, v1.z, v1.w};
        ushort_t hh[8], ll[8];
#pragma unroll
        for (int j = 0; j < 8; ++j) {
            hh[j] = f2bf(vv[j]);
            ll[j] = f2bf(vv[j] - bf2f(hh[j]));
            zsq += vv[j] * vv[j];
        }
        ushort4 h0 = {hh[0], hh[1], hh[2], hh[3]}, h1 = {hh[4], hh[5], hh[6], hh[7]};
        ushort4 l0 = {ll[0], ll[1], ll[2], ll[3]}, l1 = {ll[4], ll[5], ll[6], ll[7]};
        *(ushort4*)&Ah[s * 8] = h0;
        *(ushort4*)&Ah[s * 8 + 4] = h1;
        *(ushort4*)&Al[s * 8] = l0;
        *(ushort4*)&Al[s * 8 + 4] = l1;
    }
    zpart[w][lane] = zsq;          // r = lane for every i
    __syncthreads();

    u64 best[2][4];
#pragma unroll
    for (int rt = 0; rt < 2; ++rt)
#pragma unroll
        for (int reg = 0; reg < 4; ++reg) best[rt][reg] = ~0ull;

    for (int cb = 0; cb < 8; ++cb) {
        const int cBase = cb * 128;
        f32x4 acc[2][4];
#pragma unroll
        for (int rt = 0; rt < 2; ++rt)
#pragma unroll
            for (int ct = 0; ct < 4; ++ct) acc[rt][ct] = (f32x4){0.f, 0.f, 0.f, 0.f};

#pragma unroll
        for (int ks = 0; ks < 8; ++ks) {
            bf16x8 bfh[4], bfl[4];
            const size_t bbase = ((size_t)(ks * 4 + q) * 1024 + cBase + wcol * 64 + n16) * 8;
#pragma unroll
            for (int ct = 0; ct < 4; ++ct) {
                bfh[ct] = *(const bf16x8*)(Eph + bbase + ct * 128);
                bfl[ct] = *(const bf16x8*)(Epl + bbase + ct * 128);
            }
            bf16x8 afh[2], afl[2];
#pragma unroll
            for (int rt = 0; rt < 2; ++rt) {
                int ao = ((ks * 4 + q) * 64 + wrow * 32 + rt * 16 + n16) * 8;
                afh[rt] = *(const bf16x8*)&Ah[ao];
                afl[rt] = *(const bf16x8*)&Al[ao];
            }
#pragma unroll
            for (int rt = 0; rt < 2; ++rt)
#pragma unroll
                for (int ct = 0; ct < 4; ++ct) {
                    acc[rt][ct] = __builtin_amdgcn_mfma_f32_16x16x32_bf16(afh[rt], bfh[ct], acc[rt][ct], 0, 0, 0);
                    acc[rt][ct] = __builtin_amdgcn_mfma_f32_16x16x32_bf16(afh[rt], bfl[ct], acc[rt][ct], 0, 0, 0);
                    acc[rt][ct] = __builtin_amdgcn_mfma_f32_16x16x32_bf16(afl[rt], bfh[ct], acc[rt][ct], 0, 0, 0);
                }
        }

        // lane-local argmin update (no cross-lane work inside the cb loop)
        float cn[4];
#pragma unroll
        for (int ct = 0; ct < 4; ++ct) cn[ct] = colnorm[cBase + wcol * 64 + ct * 16 + n16];
#pragma unroll
        for (int rt = 0; rt < 2; ++rt)
#pragma unroll
            for (int reg = 0; reg < 4; ++reg) {
                u64 b = best[rt][reg];
#pragma unroll
                for (int ct = 0; ct < 4; ++ct) {
                    float dist = cn[ct] - 2.f * acc[rt][ct][reg];
                    unsigned fb = __float_as_uint(dist);
                    unsigned sk = (fb & 0x80000000u) ? ~fb : (fb | 0x80000000u);
                    unsigned code = (unsigned)(cBase + wcol * 64 + ct * 16 + n16);
                    b = umin64(b, ((u64)sk << 32) | code);
                }
                best[rt][reg] = b;
            }
    }

    // one-time cross-lane reduction within each 16-lane col group
#pragma unroll
    for (int rt = 0; rt < 2; ++rt)
#pragma unroll
        for (int reg = 0; reg < 4; ++reg) {
            u64 b = best[rt][reg];
            b = umin64(b, __shfl_xor(b, 1, 64));
            b = umin64(b, __shfl_xor(b, 2, 64));
            b = umin64(b, __shfl_xor(b, 4, 64));
            b = umin64(b, __shfl_xor(b, 8, 64));
            best[rt][reg] = b;
        }
    if (n16 == 0) {
#pragma unroll
        for (int rt = 0; rt < 2; ++rt)
#pragma unroll
            for (int reg = 0; reg < 4; ++reg)
                bl[wcol][wrow * 32 + rt * 16 + q * 4 + reg] = best[rt][reg];
    }
    __syncthreads();

    // ---- epilogue: merge wcol halves, decode key -> code + loss, hist ----
    if (t < 64) {
        u64 b = umin64(bl[0][t], bl[1][t]);
        int k = (int)(unsigned)(b & 0xFFFFFFFFull);
        unsigned sk = (unsigned)(b >> 32);
        unsigned fb = (sk & 0x80000000u) ? (sk ^ 0x80000000u) : ~sk;
        float zn = zpart[0][t] + zpart[1][t] + zpart[2][t] + zpart[3][t];
        float dmin = __uint_as_float(fb) + zn;
        idxOut[rowBase + t] = k;
        kArr[t] = k;
        atomicAdd(counts + k, 1);
        float v = dmin;
#pragma unroll
        for (int o = 32; o > 0; o >>= 1) v += __shfl_down(v, o, 64);
        if (t == 0) sred[0] = v;
    }
    __syncthreads();
    if (t == 0) atomicAdd(lossSum, sred[0]);

    // ---- gather z_q: wave w writes rows w*16..w*16+15 (no z re-read) ----
#pragma unroll
    for (int i = 0; i < 16; ++i) {
        int r = w * 16 + i;
        int k = kArr[r];
        float4 qv = *(const float4*)(ET + (size_t)k * 256 + lane * 4);
        *(float4*)(out0 + (size_t)(rowBase + r) * 256 + lane * 4) = qv;
    }
}

// ---------------- prefix scan + cluster_size_new + n + loss finalize ----------------
__global__ __launch_bounds__(1024) void prefix_csn_kernel(const int* __restrict__ counts,
                                                          const float* __restrict__ cluster_size,
                                                          const float* __restrict__ lossSum,
                                                          int* __restrict__ offsets,
                                                          int* __restrict__ cursor,
                                                          float* __restrict__ out3,
                                                          float* __restrict__ out1,
                                                          float* __restrict__ nOut) {
    __shared__ int sbuf[1024];
    int t = threadIdx.x;
    int c = counts[t];
    sbuf[t] = c;
    __syncthreads();
    for (int off = 1; off < 1024; off <<= 1) {
        int v = (t >= off) ? sbuf[t - off] : 0;
        __syncthreads();
        sbuf[t] += v;
        __syncthreads();
    }
    offsets[t] = sbuf[t] - c;
    if (t == 1023) offsets[1024] = sbuf[1023];
    cursor[t] = 0;

    float cn = cluster_size[t] * DECAYC + (1.f - DECAYC) * (float)c;
    out3[t] = cn;
    float v = cn;
#pragma unroll
    for (int o = 32; o > 0; o >>= 1) v += __shfl_down(v, o, 64);
    __shared__ float fbuf[16];
    int lane = t & 63, wv = t >> 6;
    if (lane == 0) fbuf[wv] = v;
    __syncthreads();
    if (t == 0) {
        float n = 0.f;
#pragma unroll
        for (int i = 0; i < 16; ++i) n += fbuf[i];
        nOut[0] = n;
        out1[0] = 0.25f * lossSum[0] / 16777216.0f;
    }
}

// ---------------- scatter row ids into code-sorted order ----------------
__global__ __launch_bounds__(256) void scatter_sort_kernel(const int* __restrict__ idx,
                                                           const int* __restrict__ offsets,
                                                           int* __restrict__ cursor,
                                                           int* __restrict__ sorted) {
    int i = blockIdx.x * 256 + threadIdx.x;
    int k = idx[i];
    int pos = atomicAdd(cursor + k, 1);
    sorted[offsets[k] + pos] = i;
}

// ---------------- segmented sum: psum[(k*8+s)*256+d] (no atomics) ----------------
__global__ __launch_bounds__(256) void segsum_kernel(const float* __restrict__ z,
                                                     const int* __restrict__ sorted,
                                                     const int* __restrict__ offsets,
                                                     float* __restrict__ psum) {
    const int k = blockIdx.x >> 3;
    const int s = blockIdx.x & 7;
    const int t = threadIdx.x;
    const int lane = t & 63;
    const int w = t >> 6;
    const int start = offsets[k], end = offsets[k + 1];
    float4 acc = {0.f, 0.f, 0.f, 0.f};
    for (int j = start + s * 4 + w; j < end; j += 32) {
        int row = sorted[j];
        float4 v = *(const float4*)(z + (size_t)row * 256 + lane * 4);
        acc.x += v.x; acc.y += v.y; acc.z += v.z; acc.w += v.w;
    }
    __shared__ float red[4][256];
    *(float4*)&red[w][lane * 4] = acc;
    __syncthreads();
    float v = red[0][t] + red[1][t] + red[2][t] + red[3][t];
    psum[((size_t)k * 8 + s) * 256 + t] = v;
}

// ---------------- embedding_mean_new + embedding_new ----------------
__global__ __launch_bounds__(256) void final8_kernel(const float* __restrict__ embedding_mean,
                                                     const float* __restrict__ psum,
                                                     const float* __restrict__ csn,
                                                     const float* __restrict__ nPtr,
                                                     float* __restrict__ out2,
                                                     float* __restrict__ out4) {
    int tid = blockIdx.x * 256 + threadIdx.x;
    int d = tid >> 10;
    int k = tid & 1023;
    const float* p = psum + (size_t)k * 8 * 256 + d;
    float es = 0.f;
#pragma unroll
    for (int s = 0; s < 8; ++s) es += p[s * 256];
    float emn = embedding_mean[tid] * DECAYC + (1.f - DECAYC) * es;
    out4[tid] = emn;
    float n = nPtr[0];
    float c = csn[k];
    float cs = (c + EPSQ) / (n + 1024.f * EPSQ) * n;
    out2[tid] = emn / cs;
}

extern "C" void kernel_launch(void* const* d_in, const int* in_sizes, int n_in,
                              void* d_out, int out_size, void* d_ws, size_t ws_size,
                              hipStream_t stream) {
    const float* z = (const float*)d_in[0];
    const float* E = (const float*)d_in[1];
    const float* cluster_size = (const float*)d_in[2];
    const float* embedding_mean = (const float*)d_in[3];

    float* out0 = (float*)d_out;        // z_q_st
    float* out1 = out0 + 16777216;      // vq_loss
    float* out2 = out1 + 1;             // embedding_new
    float* out3 = out2 + 262144;        // cluster_size_new
    float* out4 = out3 + 1024;          // embedding_mean_new

    // ws layout (float units)
    float* ws = (float*)d_ws;
    float* colnorm = ws;                         // 1024
    int* idx = (int*)(ws + 1024);                // 65536
    int* counts = (int*)(ws + 66560);            // 1024  (zeroed in prep_E)
    float* lossSum = ws + 67584;                 // 1     (zeroed in prep_E)
    float* nOut = ws + 67585;                    // 1
    float* ET = ws + 67588;                      // 262144 fp32 [k][d]
    ushort_t* Eph = (ushort_t*)(ws + 329732);    // 262144 ushort
    ushort_t* Epl = (ushort_t*)(ws + 460804);    // 262144 ushort
    float* psum = ws + 591876;                   // 2097152
    int* sorted = (int*)(ws + 2689028);          // 65536
    int* offsets = (int*)(ws + 2754564);         // 1025
    int* cursor = (int*)(ws + 2755592);          // 1024

    prep_E_kernel<<<1024, 256, 0, stream>>>(E, ET, colnorm, Eph, Epl, counts, lossSum);
    dist_mfma_kernel<<<1024, 256, 0, stream>>>(z, Eph, Epl, colnorm, ET,
                                               out0, lossSum, counts, idx);
    prefix_csn_kernel<<<1, 1024, 0, stream>>>(counts, cluster_size, lossSum,
                                              offsets, cursor, out3, out1, nOut);
    scatter_sort_kernel<<<256, 256, 0, stream>>>(idx, offsets, cursor, sorted);
    segsum_kernel<<<8192, 256, 0, stream>>>(z, sorted, offsets, psum);
    final8_kernel<<<1024, 256, 0, stream>>>(embedding_mean, psum, out3, nOut, out2, out4);
}